// Round 6
// baseline (648.787 us; speedup 1.0000x reference)
//
#include <hip/hip_runtime.h>
#include <hip/hip_bf16.h>

#define NN 20000
#define EE 320000
#define RR 8
#define NR (NN * RR)
#define NB 40  // scan blocks per graph: ceil(160000/4096)

typedef float f32x4 __attribute__((ext_vector_type(4)));
typedef short s16x8 __attribute__((ext_vector_type(8)));

__device__ __forceinline__ unsigned short f2bf(float f) {
  unsigned u = __builtin_bit_cast(unsigned, f);
  unsigned r = u + 0x7FFFu + ((u >> 16) & 1u);
  return (unsigned short)(r >> 16);
}
__device__ __forceinline__ float bf2f(unsigned short u) {
  return __builtin_bit_cast(float, (unsigned)u << 16);
}
__device__ __forceinline__ void gload_lds16(const void* g, void* l) {
  __builtin_amdgcn_global_load_lds(
      (const __attribute__((address_space(1))) unsigned*)g,
      (__attribute__((address_space(3))) unsigned*)l, 16, 0, 0);
}

// ---- per-(graph,dst,relation) segment count, both graphs ----
__global__ void k_count(const int* __restrict__ ei, const int* __restrict__ et,
                        int* __restrict__ cnt) {
  int e = blockIdx.x * blockDim.x + threadIdx.x;  // 0..2*EE
  int g = e >= EE;
  int el = e - g * EE;
  int d = ei[(size_t)g * 2 * EE + EE + el];
  int t = et[(size_t)g * EE + el];
  atomicAdd(&cnt[(size_t)g * NR + d * RR + t], 1);
}

// ---- hierarchical exclusive scan ----
__global__ __launch_bounds__(1024) void k_scan1(const int* __restrict__ cnt,
                                                int* __restrict__ off,
                                                int* __restrict__ btot) {
  int g = blockIdx.y, b = blockIdx.x;
  const int* c = cnt + (size_t)g * NR;
  int* o = off + (size_t)g * NR;
  __shared__ int wsum[16];
  int lane = threadIdx.x & 63, w = threadIdx.x >> 6;
  int i = b * 4096 + (int)threadIdx.x * 4;
  int4 v = {0, 0, 0, 0};
  if (i + 3 < NR) v = *(const int4*)&c[i];
  else {
    if (i < NR) v.x = c[i];
    if (i + 1 < NR) v.y = c[i + 1];
    if (i + 2 < NR) v.z = c[i + 2];
  }
  int s0 = v.x, s1 = s0 + v.y, s2 = s1 + v.z, s3 = s2 + v.w;
  int s = s3;
  for (int d = 1; d < 64; d <<= 1) {
    int t = __shfl_up(s, d);
    if (lane >= d) s += t;
  }
  if (lane == 63) wsum[w] = s;
  __syncthreads();
  if (threadIdx.x < 16) {
    int ws = wsum[threadIdx.x];
    for (int d = 1; d < 16; d <<= 1) {
      int t = __shfl_up(ws, d);
      if ((int)threadIdx.x >= d) ws += t;
    }
    wsum[threadIdx.x] = ws;
  }
  __syncthreads();
  int excl = (w > 0 ? wsum[w - 1] : 0) + (s - s3);
  if (i < NR) o[i] = excl;
  if (i + 1 < NR) o[i + 1] = excl + s0;
  if (i + 2 < NR) o[i + 2] = excl + s1;
  if (i + 3 < NR) o[i + 3] = excl + s2;
  if (threadIdx.x == 0) btot[g * NB + b] = wsum[15];
}

__global__ void k_scan2(const int* __restrict__ btot, int* __restrict__ bof) {
  int g = threadIdx.x >> 6, lane = threadIdx.x & 63;
  int v = (lane < NB) ? btot[g * NB + lane] : 0;
  int s = v;
  for (int d = 1; d < 64; d <<= 1) {
    int t = __shfl_up(s, d);
    if (lane >= d) s += t;
  }
  if (lane < NB) bof[g * NB + lane] = s - v;
}

__global__ __launch_bounds__(1024) void k_scan3(int* __restrict__ off,
                                                const int* __restrict__ bof) {
  int g = blockIdx.y;
  int add = bof[g * NB + blockIdx.x];
  int i = blockIdx.x * 4096 + (int)threadIdx.x * 4;
  int* o = off + (size_t)g * NR;
  if (i + 3 < NR) {
    int4 v = *(const int4*)&o[i];
    v.x += add; v.y += add; v.z += add; v.w += add;
    *(int4*)&o[i] = v;
  } else {
    for (int j = i; j < NR; ++j) o[j] += add;
  }
}

// ---- scatter src ids; DESTROYS off: post-scatter off[s] = end of segment s ----
__global__ void k_scatter(const int* __restrict__ ei, const int* __restrict__ et,
                          int* __restrict__ off, int* __restrict__ ssrc) {
  int e = blockIdx.x * blockDim.x + threadIdx.x;
  int g = e >= EE;
  int el = e - g * EE;
  int s = ei[(size_t)g * 2 * EE + el];
  int d = ei[(size_t)g * 2 * EE + EE + el];
  int t = et[(size_t)g * EE + el];
  int pos = atomicAdd(&off[(size_t)g * NR + d * RR + t], 1);
  ssrc[(size_t)g * EE + pos] = s;
}

// ---- fp32 x -> bf16, both graphs, into per-graph NN*256-strided slots ----
__global__ void k_cvt(const float* __restrict__ x, unsigned short* __restrict__ hX) {
  int i = (blockIdx.x * blockDim.x + threadIdx.x) * 4;
  if (i >= 2 * NN * 128) return;
  int g = i >= NN * 128;
  int il = i - g * NN * 128;
  float4 v = *(const float4*)&x[i];
  ushort4 o;
  o.x = f2bf(v.x); o.y = f2bf(v.y); o.z = f2bf(v.z); o.w = f2bf(v.w);
  *(ushort4*)&hX[(size_t)g * NN * 256 + il] = o;
}

// ---- bf16 transposed weight panel BT[co][k], k = r*Cin+ci (r=8 -> root) ----
__global__ void k_bt(const float* __restrict__ W, const float* __restrict__ root,
                     unsigned short* __restrict__ bt, int Cin, int Cout, int Ktot) {
  int idx = blockIdx.x * blockDim.x + threadIdx.x;
  if (idx >= Cout * Ktot) return;
  int co = idx / Ktot, k = idx - co * Ktot;
  int r = k / Cin, ci = k - r * Cin;
  float v = (r < RR) ? W[((size_t)r * Cin + ci) * Cout + co]
                     : root[(size_t)ci * Cout + co];
  bt[idx] = f2bf(v);
}

// ---- fused gather+GEMM: out[n,co] = lrelu( sum_r mean_r(h)[n]·W_r + h·root + b )
// A-tile: r<8 gathered on the fly from h via sorted edge segments (never hits
// HBM as a materialized matrix); r==8 staged directly from h (the root term).
template <int CIN, int COUT, bool OUTF32>
__global__ __launch_bounds__(512) void k_fused(
    const int* __restrict__ ssrc, const int* __restrict__ off,
    const unsigned short* __restrict__ h, const unsigned short* __restrict__ bt,
    const float* __restrict__ bias, void* __restrict__ outp) {
  constexpr int KTOT = (RR + 1) * CIN;
  constexpr int NWN = COUT / 64;   // n-waves per row of waves (4 or 2)
  constexpr int MF = NWN;          // m-frags per wave (wave tile = 16*MF x 64)
  constexpr int BCH = COUT * 128 / 16 / 512;  // B 16B-chunks per thread (4 or 2)
  __shared__ unsigned short As[128 * 64];
  __shared__ unsigned short Bs[COUT * 64];
  __shared__ int offs[128][9];     // per-row segment boundaries (start + 8 ends)
  const int tid = threadIdx.x, lane = tid & 63, wave = tid >> 6;
  const int wn = (wave % NWN) * 64;
  const int wm = (wave / NWN) * (16 * MF);
  const int m0 = blockIdx.x * 128;
  const int g = blockIdx.z;
  ssrc += (size_t)g * EE;
  off += (size_t)g * NR;
  h += (size_t)g * NN * 256;

  // preload per-row segment boundaries into LDS (off[s] = END of segment s)
  for (int idx = tid; idx < 128 * 9; idx += 512) {
    int row = idx / 9, j = idx - row * 9;
    int n = m0 + row;
    n = n < NN ? n : NN - 1;
    int seg0 = n * RR;
    offs[row][j] = (j == 0) ? (seg0 == 0 ? 0 : off[seg0 - 1]) : off[seg0 + j - 1];
  }
  __syncthreads();

  f32x4 acc[MF][4] = {};
  const int arow = tid >> 2;           // this thread's A row (0..127)
  const int acolb = (tid & 3) * 32;    // byte col base within 128-B row
  const int swzA = (arow & 7) << 4;
  const unsigned short* hrow = h + (tid & 3) * 16;

  for (int k0 = 0; k0 < KTOT; k0 += 64) {
    const int r = k0 / CIN, ci0 = k0 - r * CIN;
    // ---- issue B staging first (async global->LDS, hides under A gather) ----
#pragma unroll
    for (int i = 0; i < BCH; ++i) {
      int ldsb = (wave * BCH + i) * 1024;
      int Wb = ldsb + lane * 16;
      int row = Wb >> 7;
      int colb = (Wb & 127) ^ ((row & 7) << 4);
      gload_lds16((const char*)bt + ((size_t)row * KTOT + k0) * 2 + colb,
                  (char*)Bs + ldsb);
    }
    if (r == RR) {
      // ---- A: root term — stage h rows directly (async global->LDS) ----
#pragma unroll
      for (int i = 0; i < 2; ++i) {
        int ldsb = (wave * 2 + i) * 1024;
        int Wb = ldsb + lane * 16;
        int row = Wb >> 7;
        int colb = (Wb & 127) ^ ((row & 7) << 4);
        int gr = m0 + row;
        gr = gr < NN ? gr : NN - 1;
        gload_lds16((const char*)h + ((size_t)gr * CIN + ci0) * 2 + colb,
                    (char*)As + ldsb);
      }
    } else {
      // ---- A: fused per-relation mean gather (16 cols per thread) ----
      float fa[16] = {};
      int o0 = offs[arow][r], o1 = offs[arow][r + 1];
      const unsigned short* hp = hrow + ci0;
      int e = o0;
      for (; e + 1 < o1; e += 2) {
        int sa = ssrc[e], sb = ssrc[e + 1];
        s16x8 va0 = *(const s16x8*)&hp[(size_t)sa * CIN];
        s16x8 va1 = *(const s16x8*)&hp[(size_t)sa * CIN + 8];
        s16x8 vb0 = *(const s16x8*)&hp[(size_t)sb * CIN];
        s16x8 vb1 = *(const s16x8*)&hp[(size_t)sb * CIN + 8];
#pragma unroll
        for (int j = 0; j < 8; ++j) {
          fa[j] += bf2f((unsigned short)va0[j]) + bf2f((unsigned short)vb0[j]);
          fa[8 + j] += bf2f((unsigned short)va1[j]) + bf2f((unsigned short)vb1[j]);
        }
      }
      if (e < o1) {
        int sa = ssrc[e];
        s16x8 va0 = *(const s16x8*)&hp[(size_t)sa * CIN];
        s16x8 va1 = *(const s16x8*)&hp[(size_t)sa * CIN + 8];
#pragma unroll
        for (int j = 0; j < 8; ++j) {
          fa[j] += bf2f((unsigned short)va0[j]);
          fa[8 + j] += bf2f((unsigned short)va1[j]);
        }
      }
      float inv = 1.0f / fmaxf((float)(o1 - o0), 1.0f);
      s16x8 w0, w1;
#pragma unroll
      for (int j = 0; j < 8; ++j) {
        w0[j] = (short)f2bf(fa[j] * inv);
        w1[j] = (short)f2bf(fa[8 + j] * inv);
      }
      char* Ab = (char*)As + arow * 128;
      *(s16x8*)(Ab + (acolb ^ swzA)) = w0;
      *(s16x8*)(Ab + ((acolb + 16) ^ swzA)) = w1;
    }
    __syncthreads();
    // ---- MFMA ----
#pragma unroll
    for (int kk = 0; kk < 2; ++kk) {
      s16x8 a[MF], b[4];
#pragma unroll
      for (int f = 0; f < MF; ++f) {
        int row = wm + f * 16 + (lane & 15);
        int colb = kk * 64 + (lane >> 4) * 16;
        a[f] = *(const s16x8*)((const char*)As + row * 128 +
                               (colb ^ ((row & 7) << 4)));
      }
#pragma unroll
      for (int f = 0; f < 4; ++f) {
        int row = wn + f * 16 + (lane & 15);
        int colb = kk * 64 + (lane >> 4) * 16;
        b[f] = *(const s16x8*)((const char*)Bs + row * 128 +
                               (colb ^ ((row & 7) << 4)));
      }
#pragma unroll
      for (int fm = 0; fm < MF; ++fm)
#pragma unroll
        for (int fn = 0; fn < 4; ++fn)
          acc[fm][fn] = __builtin_amdgcn_mfma_f32_16x16x32_bf16(
              a[fm], b[fn], acc[fm][fn], 0, 0, 0);
    }
    __syncthreads();
  }
  // ---- epilogue: bias + LeakyReLU ----
#pragma unroll
  for (int fm = 0; fm < MF; ++fm) {
    int rbase = m0 + wm + fm * 16 + (lane >> 4) * 4;
#pragma unroll
    for (int fn = 0; fn < 4; ++fn) {
      int col = wn + fn * 16 + (lane & 15);
      float bv = bias[col];
#pragma unroll
      for (int v = 0; v < 4; ++v) {
        int row = rbase + v;
        if (row < NN) {
          float xv = acc[fm][fn][v] + bv;
          xv = xv > 0.f ? xv : 0.2f * xv;
          if constexpr (OUTF32)
            ((float*)outp)[(size_t)g * NN * COUT + (size_t)row * COUT + col] = xv;
          else
            ((unsigned short*)outp)[(size_t)g * NN * 256 + (size_t)row * COUT +
                                    col] = f2bf(xv);
        }
      }
    }
  }
}

extern "C" void kernel_launch(void* const* d_in, const int* in_sizes, int n_in,
                              void* d_out, int out_size, void* d_ws, size_t ws_size,
                              hipStream_t stream) {
  const float* x  = (const float*)d_in[0];
  const int* ei   = (const int*)d_in[1];
  const int* etp  = (const int*)d_in[2];
  const float* W0 = (const float*)d_in[3];
  const float* r0 = (const float*)d_in[4];
  const float* b0 = (const float*)d_in[5];
  const float* W1 = (const float*)d_in[6];
  const float* r1 = (const float*)d_in[7];
  const float* b1 = (const float*)d_in[8];
  const float* W2 = (const float*)d_in[9];
  const float* r2 = (const float*)d_in[10];
  const float* b2 = (const float*)d_in[11];

  char* p = (char*)d_ws;
  unsigned short* hX  = (unsigned short*)p; p += (size_t)2 * NN * 256 * 2;
  unsigned short* h_a = (unsigned short*)p; p += (size_t)2 * NN * 256 * 2;
  int* cnt  = (int*)p; p += (size_t)2 * NR * 4;
  int* off  = (int*)p; p += (size_t)2 * NR * 4;
  int* btot = (int*)p; p += (size_t)2 * NB * 4;
  int* bof  = (int*)p; p += (size_t)2 * NB * 4;
  int* ssrc = (int*)p; p += (size_t)2 * EE * 4;
  unsigned short* bt0 = (unsigned short*)p; p += (size_t)256 * 1152 * 2;
  unsigned short* bt1 = (unsigned short*)p; p += (size_t)256 * 2304 * 2;
  unsigned short* bt2 = (unsigned short*)p; p += (size_t)128 * 2304 * 2;

  // weight panels (graph-independent)
  k_bt<<<(256 * 1152 + 255) / 256, 256, 0, stream>>>(W0, r0, bt0, 128, 256, 1152);
  k_bt<<<(256 * 2304 + 255) / 256, 256, 0, stream>>>(W1, r1, bt1, 256, 256, 2304);
  k_bt<<<(128 * 2304 + 255) / 256, 256, 0, stream>>>(W2, r2, bt2, 256, 128, 2304);

  // edge sort (both graphs batched)
  (void)hipMemsetAsync(cnt, 0, (size_t)2 * NR * 4, stream);
  k_count<<<2 * EE / 256, 256, 0, stream>>>(ei, etp, cnt);
  k_scan1<<<dim3(NB, 2), 1024, 0, stream>>>(cnt, off, btot);
  k_scan2<<<1, 128, 0, stream>>>(btot, bof);
  k_scan3<<<dim3(NB, 2), 1024, 0, stream>>>(off, bof);
  k_cvt<<<2 * NN * 128 / 4 / 256, 256, 0, stream>>>(x, hX);
  k_scatter<<<2 * EE / 256, 256, 0, stream>>>(ei, etp, off, ssrc);

  // layer 0: 128 -> 256 (fused gather+GEMM)
  k_fused<128, 256, false><<<dim3(157, 1, 2), 512, 0, stream>>>(
      ssrc, off, hX, bt0, b0, h_a);
  // layer 1: 256 -> 256
  k_fused<256, 256, false><<<dim3(157, 1, 2), 512, 0, stream>>>(
      ssrc, off, h_a, bt1, b1, hX);
  // layer 2: 256 -> 128
  k_fused<256, 128, true><<<dim3(157, 1, 2), 512, 0, stream>>>(
      ssrc, off, hX, bt2, b2, d_out);
}

// Round 7
// 507.795 us; speedup vs baseline: 1.2777x; 1.2777x over previous
//
#include <hip/hip_runtime.h>
#include <hip/hip_bf16.h>

#define NN 20000
#define EE 320000
#define RR 8
#define NR (NN * RR)
#define NB 40  // scan blocks per graph: ceil(160000/4096)

typedef float f32x4 __attribute__((ext_vector_type(4)));
typedef short s16x8 __attribute__((ext_vector_type(8)));

__device__ __forceinline__ unsigned short f2bf(float f) {
  unsigned u = __builtin_bit_cast(unsigned, f);
  unsigned r = u + 0x7FFFu + ((u >> 16) & 1u);
  return (unsigned short)(r >> 16);
}
__device__ __forceinline__ float bf2f(unsigned short u) {
  return __builtin_bit_cast(float, (unsigned)u << 16);
}
__device__ __forceinline__ void gload_lds16(const void* g, void* l) {
  __builtin_amdgcn_global_load_lds(
      (const __attribute__((address_space(1))) unsigned*)g,
      (__attribute__((address_space(3))) unsigned*)l, 16, 0, 0);
}

// ---- per-(graph,dst,relation) segment count, both graphs ----
__global__ void k_count(const int* __restrict__ ei, const int* __restrict__ et,
                        int* __restrict__ cnt) {
  int e = blockIdx.x * blockDim.x + threadIdx.x;  // 0..2*EE
  int g = e >= EE;
  int el = e - g * EE;
  int d = ei[(size_t)g * 2 * EE + EE + el];
  int t = et[(size_t)g * EE + el];
  atomicAdd(&cnt[(size_t)g * NR + d * RR + t], 1);
}

// ---- hierarchical exclusive scan ----
__global__ __launch_bounds__(1024) void k_scan1(const int* __restrict__ cnt,
                                                int* __restrict__ off,
                                                int* __restrict__ btot) {
  int g = blockIdx.y, b = blockIdx.x;
  const int* c = cnt + (size_t)g * NR;
  int* o = off + (size_t)g * NR;
  __shared__ int wsum[16];
  int lane = threadIdx.x & 63, w = threadIdx.x >> 6;
  int i = b * 4096 + (int)threadIdx.x * 4;
  int4 v = {0, 0, 0, 0};
  if (i + 3 < NR) v = *(const int4*)&c[i];
  else {
    if (i < NR) v.x = c[i];
    if (i + 1 < NR) v.y = c[i + 1];
    if (i + 2 < NR) v.z = c[i + 2];
  }
  int s0 = v.x, s1 = s0 + v.y, s2 = s1 + v.z, s3 = s2 + v.w;
  int s = s3;
  for (int d = 1; d < 64; d <<= 1) {
    int t = __shfl_up(s, d);
    if (lane >= d) s += t;
  }
  if (lane == 63) wsum[w] = s;
  __syncthreads();
  if (threadIdx.x < 16) {
    int ws = wsum[threadIdx.x];
    for (int d = 1; d < 16; d <<= 1) {
      int t = __shfl_up(ws, d);
      if ((int)threadIdx.x >= d) ws += t;
    }
    wsum[threadIdx.x] = ws;
  }
  __syncthreads();
  int excl = (w > 0 ? wsum[w - 1] : 0) + (s - s3);
  if (i < NR) o[i] = excl;
  if (i + 1 < NR) o[i + 1] = excl + s0;
  if (i + 2 < NR) o[i + 2] = excl + s1;
  if (i + 3 < NR) o[i + 3] = excl + s2;
  if (threadIdx.x == 0) btot[g * NB + b] = wsum[15];
}

__global__ void k_scan2(const int* __restrict__ btot, int* __restrict__ bof) {
  int g = threadIdx.x >> 6, lane = threadIdx.x & 63;
  int v = (lane < NB) ? btot[g * NB + lane] : 0;
  int s = v;
  for (int d = 1; d < 64; d <<= 1) {
    int t = __shfl_up(s, d);
    if (lane >= d) s += t;
  }
  if (lane < NB) bof[g * NB + lane] = s - v;
}

__global__ __launch_bounds__(1024) void k_scan3(int* __restrict__ off,
                                                const int* __restrict__ bof) {
  int g = blockIdx.y;
  int add = bof[g * NB + blockIdx.x];
  int i = blockIdx.x * 4096 + (int)threadIdx.x * 4;
  int* o = off + (size_t)g * NR;
  if (i + 3 < NR) {
    int4 v = *(const int4*)&o[i];
    v.x += add; v.y += add; v.z += add; v.w += add;
    *(int4*)&o[i] = v;
  } else {
    for (int j = i; j < NR; ++j) o[j] += add;
  }
}

// ---- scatter src ids; DESTROYS off: post-scatter off[s] = end of segment s ----
__global__ void k_scatter(const int* __restrict__ ei, const int* __restrict__ et,
                          int* __restrict__ off, int* __restrict__ ssrc) {
  int e = blockIdx.x * blockDim.x + threadIdx.x;
  int g = e >= EE;
  int el = e - g * EE;
  int s = ei[(size_t)g * 2 * EE + el];
  int d = ei[(size_t)g * 2 * EE + EE + el];
  int t = et[(size_t)g * EE + el];
  int pos = atomicAdd(&off[(size_t)g * NR + d * RR + t], 1);
  ssrc[(size_t)g * EE + pos] = s;
}

// ---- fp32 x -> bf16, both graphs, into per-graph NN*256-strided slots ----
__global__ void k_cvt(const float* __restrict__ x, unsigned short* __restrict__ hX) {
  int i = (blockIdx.x * blockDim.x + threadIdx.x) * 4;
  if (i >= 2 * NN * 128) return;
  int g = i >= NN * 128;
  int il = i - g * NN * 128;
  float4 v = *(const float4*)&x[i];
  ushort4 o;
  o.x = f2bf(v.x); o.y = f2bf(v.y); o.z = f2bf(v.z); o.w = f2bf(v.w);
  *(ushort4*)&hX[(size_t)g * NN * 256 + il] = o;
}

// ---- bf16 transposed weight panel BT[co][k], k = r*Cin+ci (r=8 -> root) ----
__global__ void k_bt(const float* __restrict__ W, const float* __restrict__ root,
                     unsigned short* __restrict__ bt, int Cin, int Cout, int Ktot) {
  int idx = blockIdx.x * blockDim.x + threadIdx.x;
  if (idx >= Cout * Ktot) return;
  int co = idx / Ktot, k = idx - co * Ktot;
  int r = k / Cin, ci = k - r * Cin;
  float v = (r < RR) ? W[((size_t)r * Cin + ci) * Cout + co]
                     : root[(size_t)ci * Cout + co];
  bt[idx] = f2bf(v);
}

// MFMA on the current 64-row x COUT x 64-K tile in LDS
#define MFMA_STEP()                                                            \
  do {                                                                         \
    _Pragma("unroll") for (int kk = 0; kk < 2; ++kk) {                         \
      s16x8 a[MF], b[4];                                                       \
      _Pragma("unroll") for (int f = 0; f < MF; ++f) {                         \
        int row = wm + f * 16 + (lane & 15);                                   \
        int colb = kk * 64 + (lane >> 4) * 16;                                 \
        a[f] = *(const s16x8*)((const char*)As + row * 128 +                   \
                               (colb ^ ((row & 7) << 4)));                     \
      }                                                                        \
      _Pragma("unroll") for (int f = 0; f < 4; ++f) {                          \
        int row = wn + f * 16 + (lane & 15);                                   \
        int colb = kk * 64 + (lane >> 4) * 16;                                 \
        b[f] = *(const s16x8*)((const char*)Bs + row * 128 +                   \
                               (colb ^ ((row & 7) << 4)));                     \
      }                                                                        \
      _Pragma("unroll") for (int fm = 0; fm < MF; ++fm)                        \
          _Pragma("unroll") for (int fn = 0; fn < 4; ++fn)                     \
              acc[fm][fn] = __builtin_amdgcn_mfma_f32_16x16x32_bf16(           \
                  a[fm], b[fn], acc[fm][fn], 0, 0, 0);                         \
    }                                                                          \
  } while (0)

// ---- fused gather+GEMM, 64-row x COUT tile, walk-once-per-relation ----
// out[n,co] = lrelu( sum_r mean_r(h)[n]·W_r + h·root + b )
template <int CIN, int COUT, bool OUTF32>
__global__ __launch_bounds__(256, 2) void k_fused(
    const int* __restrict__ ssrc, const int* __restrict__ off,
    const unsigned short* __restrict__ h, const unsigned short* __restrict__ bt,
    const float* __restrict__ bias, void* __restrict__ outp) {
  constexpr int KTOT = (RR + 1) * CIN;
  constexpr int CH = CIN / 64;     // K-steps per relation (2 or 4)
  constexpr int NWN = COUT / 64;   // n-waves (4 or 2)
  constexpr int MW = 4 / NWN;      // m-waves (1 or 2)
  constexpr int WR = 64 / MW;      // rows per wave
  constexpr int MF = WR / 16;      // m-frags per wave (4 or 2)
  constexpr int BCH = COUT / 32;   // B 16B-chunks per thread (8 or 4)
  __shared__ unsigned short As[64 * 64];
  __shared__ unsigned short Bs[COUT * 64];
  __shared__ int offs[64][9];      // per-row segment boundaries (start + 8 ends)
  const int tid = threadIdx.x, lane = tid & 63, wave = tid >> 6;
  const int wn = (wave % NWN) * 64;
  const int wm = (wave / NWN) * WR;
  const int m0 = blockIdx.x * 64;
  const int g = blockIdx.z;
  ssrc += (size_t)g * EE;
  off += (size_t)g * NR;
  h += (size_t)g * NN * 256;

  for (int idx = tid; idx < 64 * 9; idx += 256) {
    int row = idx / 9, j = idx - row * 9;
    int n = m0 + row;
    n = n < NN ? n : NN - 1;
    int seg0 = n * RR;
    offs[row][j] = (j == 0) ? (seg0 == 0 ? 0 : off[seg0 - 1]) : off[seg0 + j - 1];
  }
  __syncthreads();

  f32x4 acc[MF][4] = {};
  const int arow = tid >> 2;        // this thread's A row (0..63)
  const int q = tid & 3;            // 4 threads per row, 16 cols each per chunk
  const int swzA = (arow & 7) << 4;
  const unsigned short* hq = h + q * 16;

  for (int r = 0; r < RR; ++r) {
    // ---- walk this relation's segment ONCE, full-CIN fp32 accumulation ----
    float fa[CH][16];
#pragma unroll
    for (int c = 0; c < CH; ++c)
#pragma unroll
      for (int j = 0; j < 16; ++j) fa[c][j] = 0.f;
    int o0 = offs[arow][r], o1 = offs[arow][r + 1];
    int e = o0;
    for (; e + 1 < o1; e += 2) {
      int sa = ssrc[e], sb = ssrc[e + 1];
      const unsigned short* pa = hq + (size_t)sa * CIN;
      const unsigned short* pb = hq + (size_t)sb * CIN;
#pragma unroll
      for (int c = 0; c < CH; ++c) {
        s16x8 va0 = *(const s16x8*)(pa + c * 64);
        s16x8 va1 = *(const s16x8*)(pa + c * 64 + 8);
        s16x8 vb0 = *(const s16x8*)(pb + c * 64);
        s16x8 vb1 = *(const s16x8*)(pb + c * 64 + 8);
#pragma unroll
        for (int j = 0; j < 8; ++j) {
          fa[c][j] += bf2f((unsigned short)va0[j]) + bf2f((unsigned short)vb0[j]);
          fa[c][8 + j] += bf2f((unsigned short)va1[j]) + bf2f((unsigned short)vb1[j]);
        }
      }
    }
    if (e < o1) {
      int sa = ssrc[e];
      const unsigned short* pa = hq + (size_t)sa * CIN;
#pragma unroll
      for (int c = 0; c < CH; ++c) {
        s16x8 va0 = *(const s16x8*)(pa + c * 64);
        s16x8 va1 = *(const s16x8*)(pa + c * 64 + 8);
#pragma unroll
        for (int j = 0; j < 8; ++j) {
          fa[c][j] += bf2f((unsigned short)va0[j]);
          fa[c][8 + j] += bf2f((unsigned short)va1[j]);
        }
      }
    }
    float inv = 1.0f / fmaxf((float)(o1 - o0), 1.0f);
    s16x8 mb[CH][2];
#pragma unroll
    for (int c = 0; c < CH; ++c)
#pragma unroll
      for (int j = 0; j < 8; ++j) {
        mb[c][0][j] = (short)f2bf(fa[c][j] * inv);
        mb[c][1][j] = (short)f2bf(fa[c][8 + j] * inv);
      }
    // ---- drain: CH K-steps of 64 cols each ----
#pragma unroll
    for (int c = 0; c < CH; ++c) {
      const int k0 = r * CIN + c * 64;
#pragma unroll
      for (int i = 0; i < BCH; ++i) {
        int ldsb = (wave * BCH + i) * 1024;
        int Wb = ldsb + lane * 16;
        int brow = Wb >> 7;
        int colb = (Wb & 127) ^ ((brow & 7) << 4);
        gload_lds16((const char*)bt + ((size_t)brow * KTOT + k0) * 2 + colb,
                    (char*)Bs + ldsb);
      }
      char* Ab = (char*)As + arow * 128;
      *(s16x8*)(Ab + ((q * 32) ^ swzA)) = mb[c][0];
      *(s16x8*)(Ab + ((q * 32 + 16) ^ swzA)) = mb[c][1];
      __syncthreads();
      MFMA_STEP();
      __syncthreads();
    }
  }
  // ---- root term: stage A directly from h ----
#pragma unroll
  for (int c = 0; c < CH; ++c) {
    const int k0 = RR * CIN + c * 64;
#pragma unroll
    for (int i = 0; i < BCH; ++i) {
      int ldsb = (wave * BCH + i) * 1024;
      int Wb = ldsb + lane * 16;
      int brow = Wb >> 7;
      int colb = (Wb & 127) ^ ((brow & 7) << 4);
      gload_lds16((const char*)bt + ((size_t)brow * KTOT + k0) * 2 + colb,
                  (char*)Bs + ldsb);
    }
#pragma unroll
    for (int i = 0; i < 2; ++i) {
      int ldsb = (wave * 2 + i) * 1024;
      int Wb = ldsb + lane * 16;
      int row = Wb >> 7;
      int colb = (Wb & 127) ^ ((row & 7) << 4);
      int gr = m0 + row;
      gr = gr < NN ? gr : NN - 1;
      gload_lds16((const char*)h + ((size_t)gr * CIN + c * 64) * 2 + colb,
                  (char*)As + ldsb);
    }
    __syncthreads();
    MFMA_STEP();
    __syncthreads();
  }
  // ---- epilogue: bias + LeakyReLU ----
#pragma unroll
  for (int fm = 0; fm < MF; ++fm) {
    int rbase = m0 + wm + fm * 16 + (lane >> 4) * 4;
#pragma unroll
    for (int fn = 0; fn < 4; ++fn) {
      int col = wn + fn * 16 + (lane & 15);
      float bv = bias[col];
#pragma unroll
      for (int v = 0; v < 4; ++v) {
        int row = rbase + v;
        if (row < NN) {
          float xv = acc[fm][fn][v] + bv;
          xv = xv > 0.f ? xv : 0.2f * xv;
          if constexpr (OUTF32)
            ((float*)outp)[(size_t)g * NN * COUT + (size_t)row * COUT + col] = xv;
          else
            ((unsigned short*)outp)[(size_t)g * NN * 256 + (size_t)row * COUT +
                                    col] = f2bf(xv);
        }
      }
    }
  }
}

extern "C" void kernel_launch(void* const* d_in, const int* in_sizes, int n_in,
                              void* d_out, int out_size, void* d_ws, size_t ws_size,
                              hipStream_t stream) {
  const float* x  = (const float*)d_in[0];
  const int* ei   = (const int*)d_in[1];
  const int* etp  = (const int*)d_in[2];
  const float* W0 = (const float*)d_in[3];
  const float* r0 = (const float*)d_in[4];
  const float* b0 = (const float*)d_in[5];
  const float* W1 = (const float*)d_in[6];
  const float* r1 = (const float*)d_in[7];
  const float* b1 = (const float*)d_in[8];
  const float* W2 = (const float*)d_in[9];
  const float* r2 = (const float*)d_in[10];
  const float* b2 = (const float*)d_in[11];

  char* p = (char*)d_ws;
  unsigned short* hX  = (unsigned short*)p; p += (size_t)2 * NN * 256 * 2;
  unsigned short* h_a = (unsigned short*)p; p += (size_t)2 * NN * 256 * 2;
  int* cnt  = (int*)p; p += (size_t)2 * NR * 4;
  int* off  = (int*)p; p += (size_t)2 * NR * 4;
  int* btot = (int*)p; p += (size_t)2 * NB * 4;
  int* bof  = (int*)p; p += (size_t)2 * NB * 4;
  int* ssrc = (int*)p; p += (size_t)2 * EE * 4;
  unsigned short* bt0 = (unsigned short*)p; p += (size_t)256 * 1152 * 2;
  unsigned short* bt1 = (unsigned short*)p; p += (size_t)256 * 2304 * 2;
  unsigned short* bt2 = (unsigned short*)p; p += (size_t)128 * 2304 * 2;

  // weight panels (graph-independent)
  k_bt<<<(256 * 1152 + 255) / 256, 256, 0, stream>>>(W0, r0, bt0, 128, 256, 1152);
  k_bt<<<(256 * 2304 + 255) / 256, 256, 0, stream>>>(W1, r1, bt1, 256, 256, 2304);
  k_bt<<<(128 * 2304 + 255) / 256, 256, 0, stream>>>(W2, r2, bt2, 256, 128, 2304);

  // edge sort (both graphs batched)
  (void)hipMemsetAsync(cnt, 0, (size_t)2 * NR * 4, stream);
  k_count<<<2 * EE / 256, 256, 0, stream>>>(ei, etp, cnt);
  k_scan1<<<dim3(NB, 2), 1024, 0, stream>>>(cnt, off, btot);
  k_scan2<<<1, 128, 0, stream>>>(btot, bof);
  k_scan3<<<dim3(NB, 2), 1024, 0, stream>>>(off, bof);
  k_cvt<<<2 * NN * 128 / 4 / 256, 256, 0, stream>>>(x, hX);
  k_scatter<<<2 * EE / 256, 256, 0, stream>>>(ei, etp, off, ssrc);

  // layer 0: 128 -> 256 (fused gather+GEMM)
  k_fused<128, 256, false><<<dim3(313, 1, 2), 256, 0, stream>>>(
      ssrc, off, hX, bt0, b0, h_a);
  // layer 1: 256 -> 256
  k_fused<256, 256, false><<<dim3(313, 1, 2), 256, 0, stream>>>(
      ssrc, off, h_a, bt1, b1, hX);
  // layer 2: 256 -> 128
  k_fused<256, 128, true><<<dim3(313, 1, 2), 256, 0, stream>>>(
      ssrc, off, hX, bt2, b2, d_out);
}

// Round 8
// 471.993 us; speedup vs baseline: 1.3746x; 1.0759x over previous
//
#include <hip/hip_runtime.h>
#include <hip/hip_bf16.h>

#define NN 20000
#define EE 320000
#define RR 8
#define NR (NN * RR)
#define NB 40    // scan blocks per graph: ceil(160000/4096)
#define SCAP 2048  // LDS edge-window capacity (mean 1024, sd 32)

typedef float f32x4 __attribute__((ext_vector_type(4)));
typedef short s16x8 __attribute__((ext_vector_type(8)));

__device__ __forceinline__ unsigned short f2bf(float f) {
  unsigned u = __builtin_bit_cast(unsigned, f);
  unsigned r = u + 0x7FFFu + ((u >> 16) & 1u);
  return (unsigned short)(r >> 16);
}
__device__ __forceinline__ float bf2f(unsigned short u) {
  return __builtin_bit_cast(float, (unsigned)u << 16);
}
__device__ __forceinline__ void gload_lds16(const void* g, void* l) {
  __builtin_amdgcn_global_load_lds(
      (const __attribute__((address_space(1))) unsigned*)g,
      (__attribute__((address_space(3))) unsigned*)l, 16, 0, 0);
}

// ---- per-(graph,dst,relation) segment count, both graphs ----
__global__ void k_count(const int* __restrict__ ei, const int* __restrict__ et,
                        int* __restrict__ cnt) {
  int e = blockIdx.x * blockDim.x + threadIdx.x;  // 0..2*EE
  int g = e >= EE;
  int el = e - g * EE;
  int d = ei[(size_t)g * 2 * EE + EE + el];
  int t = et[(size_t)g * EE + el];
  atomicAdd(&cnt[(size_t)g * NR + d * RR + t], 1);
}

// ---- hierarchical exclusive scan ----
__global__ __launch_bounds__(1024) void k_scan1(const int* __restrict__ cnt,
                                                int* __restrict__ off,
                                                int* __restrict__ btot) {
  int g = blockIdx.y, b = blockIdx.x;
  const int* c = cnt + (size_t)g * NR;
  int* o = off + (size_t)g * NR;
  __shared__ int wsum[16];
  int lane = threadIdx.x & 63, w = threadIdx.x >> 6;
  int i = b * 4096 + (int)threadIdx.x * 4;
  int4 v = {0, 0, 0, 0};
  if (i + 3 < NR) v = *(const int4*)&c[i];
  else {
    if (i < NR) v.x = c[i];
    if (i + 1 < NR) v.y = c[i + 1];
    if (i + 2 < NR) v.z = c[i + 2];
  }
  int s0 = v.x, s1 = s0 + v.y, s2 = s1 + v.z, s3 = s2 + v.w;
  int s = s3;
  for (int d = 1; d < 64; d <<= 1) {
    int t = __shfl_up(s, d);
    if (lane >= d) s += t;
  }
  if (lane == 63) wsum[w] = s;
  __syncthreads();
  if (threadIdx.x < 16) {
    int ws = wsum[threadIdx.x];
    for (int d = 1; d < 16; d <<= 1) {
      int t = __shfl_up(ws, d);
      if ((int)threadIdx.x >= d) ws += t;
    }
    wsum[threadIdx.x] = ws;
  }
  __syncthreads();
  int excl = (w > 0 ? wsum[w - 1] : 0) + (s - s3);
  if (i < NR) o[i] = excl;
  if (i + 1 < NR) o[i + 1] = excl + s0;
  if (i + 2 < NR) o[i + 2] = excl + s1;
  if (i + 3 < NR) o[i + 3] = excl + s2;
  if (threadIdx.x == 0) btot[g * NB + b] = wsum[15];
}

__global__ void k_scan2(const int* __restrict__ btot, int* __restrict__ bof) {
  int g = threadIdx.x >> 6, lane = threadIdx.x & 63;
  int v = (lane < NB) ? btot[g * NB + lane] : 0;
  int s = v;
  for (int d = 1; d < 64; d <<= 1) {
    int t = __shfl_up(s, d);
    if (lane >= d) s += t;
  }
  if (lane < NB) bof[g * NB + lane] = s - v;
}

__global__ __launch_bounds__(1024) void k_scan3(int* __restrict__ off,
                                                const int* __restrict__ bof) {
  int g = blockIdx.y;
  int add = bof[g * NB + blockIdx.x];
  int i = blockIdx.x * 4096 + (int)threadIdx.x * 4;
  int* o = off + (size_t)g * NR;
  if (i + 3 < NR) {
    int4 v = *(const int4*)&o[i];
    v.x += add; v.y += add; v.z += add; v.w += add;
    *(int4*)&o[i] = v;
  } else {
    for (int j = i; j < NR; ++j) o[j] += add;
  }
}

// ---- scatter src ids; DESTROYS off: post-scatter off[s] = end of segment s ----
__global__ void k_scatter(const int* __restrict__ ei, const int* __restrict__ et,
                          int* __restrict__ off, int* __restrict__ ssrc) {
  int e = blockIdx.x * blockDim.x + threadIdx.x;
  int g = e >= EE;
  int el = e - g * EE;
  int s = ei[(size_t)g * 2 * EE + el];
  int d = ei[(size_t)g * 2 * EE + EE + el];
  int t = et[(size_t)g * EE + el];
  int pos = atomicAdd(&off[(size_t)g * NR + d * RR + t], 1);
  ssrc[(size_t)g * EE + pos] = s;
}

// ---- fp32 x -> bf16, both graphs, into per-graph NN*256-strided slots ----
__global__ void k_cvt(const float* __restrict__ x, unsigned short* __restrict__ hX) {
  int i = (blockIdx.x * blockDim.x + threadIdx.x) * 4;
  if (i >= 2 * NN * 128) return;
  int g = i >= NN * 128;
  int il = i - g * NN * 128;
  float4 v = *(const float4*)&x[i];
  ushort4 o;
  o.x = f2bf(v.x); o.y = f2bf(v.y); o.z = f2bf(v.z); o.w = f2bf(v.w);
  *(ushort4*)&hX[(size_t)g * NN * 256 + il] = o;
}

// ---- bf16 transposed weight panel BT[co][k], k = r*Cin+ci (r=8 -> root) ----
__global__ void k_bt(const float* __restrict__ W, const float* __restrict__ root,
                     unsigned short* __restrict__ bt, int Cin, int Cout, int Ktot) {
  int idx = blockIdx.x * blockDim.x + threadIdx.x;
  if (idx >= Cout * Ktot) return;
  int co = idx / Ktot, k = idx - co * Ktot;
  int r = k / Cin, ci = k - r * Cin;
  float v = (r < RR) ? W[((size_t)r * Cin + ci) * Cout + co]
                     : root[(size_t)ci * Cout + co];
  bt[idx] = f2bf(v);
}

// MFMA on the current 64-row x COUT x 64-K tile in LDS
#define MFMA_STEP()                                                            \
  do {                                                                         \
    _Pragma("unroll") for (int kk = 0; kk < 2; ++kk) {                         \
      s16x8 a[MF], b[4];                                                       \
      _Pragma("unroll") for (int f = 0; f < MF; ++f) {                         \
        int row = wm + f * 16 + (lane & 15);                                   \
        int colb = kk * 64 + (lane >> 4) * 16;                                 \
        a[f] = *(const s16x8*)((const char*)As + row * 128 +                   \
                               (colb ^ ((row & 7) << 4)));                     \
      }                                                                        \
      _Pragma("unroll") for (int f = 0; f < 4; ++f) {                          \
        int row = wn + f * 16 + (lane & 15);                                   \
        int colb = kk * 64 + (lane >> 4) * 16;                                 \
        b[f] = *(const s16x8*)((const char*)Bs + row * 128 +                   \
                               (colb ^ ((row & 7) << 4)));                     \
      }                                                                        \
      _Pragma("unroll") for (int fm = 0; fm < MF; ++fm)                        \
          _Pragma("unroll") for (int fn = 0; fn < 4; ++fn)                     \
              acc[fm][fn] = __builtin_amdgcn_mfma_f32_16x16x32_bf16(           \
                  a[fm], b[fn], acc[fm][fn], 0, 0, 0);                         \
    }                                                                          \
  } while (0)

// ---- fused gather+GEMM, 64-row x COUT tile, walk-once-per-relation,
//      block edge-window cached in LDS ----
template <int CIN, int COUT, bool OUTF32>
__global__ __launch_bounds__(256, 3) void k_fused(
    const int* __restrict__ ssrc, const int* __restrict__ off,
    const unsigned short* __restrict__ h, const unsigned short* __restrict__ bt,
    const float* __restrict__ bias, void* __restrict__ outp) {
  constexpr int KTOT = (RR + 1) * CIN;
  constexpr int CH = CIN / 64;     // K-steps per relation (2 or 4)
  constexpr int NWN = COUT / 64;   // n-waves (4 or 2)
  constexpr int MW = 4 / NWN;      // m-waves (1 or 2)
  constexpr int WR = 64 / MW;      // rows per wave
  constexpr int MF = WR / 16;      // m-frags per wave (4 or 2)
  constexpr int BCH = COUT / 32;   // B 16B-chunks per thread (8 or 4)
  __shared__ unsigned short As[64 * 64];
  __shared__ unsigned short Bs[COUT * 64];
  __shared__ int offs[64][9];      // per-row segment boundaries (start + 8 ends)
  __shared__ int sseg[SCAP];       // this block's sorted-edge window
  const int tid = threadIdx.x, lane = tid & 63, wave = tid >> 6;
  const int wn = (wave % NWN) * 64;
  const int wm = (wave / NWN) * WR;
  const int m0 = blockIdx.x * 64;
  const int g = blockIdx.z;
  ssrc += (size_t)g * EE;
  off += (size_t)g * NR;
  h += (size_t)g * NN * 256;

  for (int idx = tid; idx < 64 * 9; idx += 256) {
    int row = idx / 9, j = idx - row * 9;
    int n = m0 + row;
    n = n < NN ? n : NN - 1;
    int seg0 = n * RR;
    offs[row][j] = (j == 0) ? (seg0 == 0 ? 0 : off[seg0 - 1]) : off[seg0 + j - 1];
  }
  // block edge window [ebase, eend): all rows' segments are contiguous in ssrc
  const int segA = m0 * RR;
  const int segB = (m0 + 64 < NN ? m0 + 64 : NN) * RR;
  const int ebase = (segA == 0) ? 0 : off[segA - 1];
  const int eend = off[segB - 1];
  const int cntE = eend - ebase;
  const bool inl = cntE <= SCAP;
  if (inl)
    for (int i = tid; i < cntE; i += 256) sseg[i] = ssrc[ebase + i];
  __syncthreads();

  f32x4 acc[MF][4] = {};
  const int arow = tid >> 2;        // this thread's A row (0..63)
  const int q = tid & 3;            // 4 threads per row, 16 cols each per chunk
  const int swzA = (arow & 7) << 4;
  const unsigned short* hq = h + q * 16;

  for (int r = 0; r < RR; ++r) {
    // ---- walk this relation's segment ONCE, full-CIN fp32 accumulation ----
    float fa[CH][16];
#pragma unroll
    for (int c = 0; c < CH; ++c)
#pragma unroll
      for (int j = 0; j < 16; ++j) fa[c][j] = 0.f;
    int o0 = offs[arow][r], o1 = offs[arow][r + 1];
    int e = o0;
    for (; e + 1 < o1; e += 2) {
      int sa = inl ? sseg[e - ebase] : ssrc[e];
      int sb = inl ? sseg[e + 1 - ebase] : ssrc[e + 1];
      const unsigned short* pa = hq + (size_t)sa * CIN;
      const unsigned short* pb = hq + (size_t)sb * CIN;
#pragma unroll
      for (int c = 0; c < CH; ++c) {
        s16x8 va0 = *(const s16x8*)(pa + c * 64);
        s16x8 va1 = *(const s16x8*)(pa + c * 64 + 8);
        s16x8 vb0 = *(const s16x8*)(pb + c * 64);
        s16x8 vb1 = *(const s16x8*)(pb + c * 64 + 8);
#pragma unroll
        for (int j = 0; j < 8; ++j) {
          fa[c][j] += bf2f((unsigned short)va0[j]) + bf2f((unsigned short)vb0[j]);
          fa[c][8 + j] += bf2f((unsigned short)va1[j]) + bf2f((unsigned short)vb1[j]);
        }
      }
    }
    if (e < o1) {
      int sa = inl ? sseg[e - ebase] : ssrc[e];
      const unsigned short* pa = hq + (size_t)sa * CIN;
#pragma unroll
      for (int c = 0; c < CH; ++c) {
        s16x8 va0 = *(const s16x8*)(pa + c * 64);
        s16x8 va1 = *(const s16x8*)(pa + c * 64 + 8);
#pragma unroll
        for (int j = 0; j < 8; ++j) {
          fa[c][j] += bf2f((unsigned short)va0[j]);
          fa[c][8 + j] += bf2f((unsigned short)va1[j]);
        }
      }
    }
    float inv = 1.0f / fmaxf((float)(o1 - o0), 1.0f);
    s16x8 mb[CH][2];
#pragma unroll
    for (int c = 0; c < CH; ++c)
#pragma unroll
      for (int j = 0; j < 8; ++j) {
        mb[c][0][j] = (short)f2bf(fa[c][j] * inv);
        mb[c][1][j] = (short)f2bf(fa[c][8 + j] * inv);
      }
    // ---- drain: CH K-steps of 64 cols each ----
#pragma unroll
    for (int c = 0; c < CH; ++c) {
      const int k0 = r * CIN + c * 64;
#pragma unroll
      for (int i = 0; i < BCH; ++i) {
        int ldsb = (wave * BCH + i) * 1024;
        int Wb = ldsb + lane * 16;
        int brow = Wb >> 7;
        int colb = (Wb & 127) ^ ((brow & 7) << 4);
        gload_lds16((const char*)bt + ((size_t)brow * KTOT + k0) * 2 + colb,
                    (char*)Bs + ldsb);
      }
      char* Ab = (char*)As + arow * 128;
      *(s16x8*)(Ab + ((q * 32) ^ swzA)) = mb[c][0];
      *(s16x8*)(Ab + ((q * 32 + 16) ^ swzA)) = mb[c][1];
      __syncthreads();
      MFMA_STEP();
      __syncthreads();
    }
  }
  // ---- root term: stage A directly from h ----
#pragma unroll
  for (int c = 0; c < CH; ++c) {
    const int k0 = RR * CIN + c * 64;
#pragma unroll
    for (int i = 0; i < BCH; ++i) {
      int ldsb = (wave * BCH + i) * 1024;
      int Wb = ldsb + lane * 16;
      int brow = Wb >> 7;
      int colb = (Wb & 127) ^ ((brow & 7) << 4);
      gload_lds16((const char*)bt + ((size_t)brow * KTOT + k0) * 2 + colb,
                  (char*)Bs + ldsb);
    }
#pragma unroll
    for (int i = 0; i < 2; ++i) {
      int ldsb = (wave * 2 + i) * 1024;
      int Wb = ldsb + lane * 16;
      int row = Wb >> 7;
      int colb = (Wb & 127) ^ ((row & 7) << 4);
      int gr = m0 + row;
      gr = gr < NN ? gr : NN - 1;
      gload_lds16((const char*)h + ((size_t)gr * CIN + c * 64) * 2 + colb,
                  (char*)As + ldsb);
    }
    __syncthreads();
    MFMA_STEP();
    __syncthreads();
  }
  // ---- epilogue: bias + LeakyReLU ----
#pragma unroll
  for (int fm = 0; fm < MF; ++fm) {
    int rbase = m0 + wm + fm * 16 + (lane >> 4) * 4;
#pragma unroll
    for (int fn = 0; fn < 4; ++fn) {
      int col = wn + fn * 16 + (lane & 15);
      float bv = bias[col];
#pragma unroll
      for (int v = 0; v < 4; ++v) {
        int row = rbase + v;
        if (row < NN) {
          float xv = acc[fm][fn][v] + bv;
          xv = xv > 0.f ? xv : 0.2f * xv;
          if constexpr (OUTF32)
            ((float*)outp)[(size_t)g * NN * COUT + (size_t)row * COUT + col] = xv;
          else
            ((unsigned short*)outp)[(size_t)g * NN * 256 + (size_t)row * COUT +
                                    col] = f2bf(xv);
        }
      }
    }
  }
}

extern "C" void kernel_launch(void* const* d_in, const int* in_sizes, int n_in,
                              void* d_out, int out_size, void* d_ws, size_t ws_size,
                              hipStream_t stream) {
  const float* x  = (const float*)d_in[0];
  const int* ei   = (const int*)d_in[1];
  const int* etp  = (const int*)d_in[2];
  const float* W0 = (const float*)d_in[3];
  const float* r0 = (const float*)d_in[4];
  const float* b0 = (const float*)d_in[5];
  const float* W1 = (const float*)d_in[6];
  const float* r1 = (const float*)d_in[7];
  const float* b1 = (const float*)d_in[8];
  const float* W2 = (const float*)d_in[9];
  const float* r2 = (const float*)d_in[10];
  const float* b2 = (const float*)d_in[11];

  char* p = (char*)d_ws;
  unsigned short* hX  = (unsigned short*)p; p += (size_t)2 * NN * 256 * 2;
  unsigned short* h_a = (unsigned short*)p; p += (size_t)2 * NN * 256 * 2;
  int* cnt  = (int*)p; p += (size_t)2 * NR * 4;
  int* off  = (int*)p; p += (size_t)2 * NR * 4;
  int* btot = (int*)p; p += (size_t)2 * NB * 4;
  int* bof  = (int*)p; p += (size_t)2 * NB * 4;
  int* ssrc = (int*)p; p += (size_t)2 * EE * 4;
  unsigned short* bt0 = (unsigned short*)p; p += (size_t)256 * 1152 * 2;
  unsigned short* bt1 = (unsigned short*)p; p += (size_t)256 * 2304 * 2;
  unsigned short* bt2 = (unsigned short*)p; p += (size_t)128 * 2304 * 2;

  // weight panels (graph-independent)
  k_bt<<<(256 * 1152 + 255) / 256, 256, 0, stream>>>(W0, r0, bt0, 128, 256, 1152);
  k_bt<<<(256 * 2304 + 255) / 256, 256, 0, stream>>>(W1, r1, bt1, 256, 256, 2304);
  k_bt<<<(128 * 2304 + 255) / 256, 256, 0, stream>>>(W2, r2, bt2, 256, 128, 2304);

  // edge sort (both graphs batched)
  (void)hipMemsetAsync(cnt, 0, (size_t)2 * NR * 4, stream);
  k_count<<<2 * EE / 256, 256, 0, stream>>>(ei, etp, cnt);
  k_scan1<<<dim3(NB, 2), 1024, 0, stream>>>(cnt, off, btot);
  k_scan2<<<1, 128, 0, stream>>>(btot, bof);
  k_scan3<<<dim3(NB, 2), 1024, 0, stream>>>(off, bof);
  k_cvt<<<2 * NN * 128 / 4 / 256, 256, 0, stream>>>(x, hX);
  k_scatter<<<2 * EE / 256, 256, 0, stream>>>(ei, etp, off, ssrc);

  // layer 0: 128 -> 256 (fused gather+GEMM)
  k_fused<128, 256, false><<<dim3(313, 1, 2), 256, 0, stream>>>(
      ssrc, off, hX, bt0, b0, h_a);
  // layer 1: 256 -> 256
  k_fused<256, 256, false><<<dim3(313, 1, 2), 256, 0, stream>>>(
      ssrc, off, h_a, bt1, b1, hX);
  // layer 2: 256 -> 128
  k_fused<256, 128, true><<<dim3(313, 1, 2), 256, 0, stream>>>(
      ssrc, off, hX, bt2, b2, d_out);
}

// Round 9
// 453.790 us; speedup vs baseline: 1.4297x; 1.0401x over previous
//
#include <hip/hip_runtime.h>
#include <hip/hip_bf16.h>

#define NN 20000
#define EE 320000
#define RR 8
#define NR (NN * RR)
#define NB 40     // scan blocks per graph: ceil(160000/4096)
#define SCAP 640  // LDS edge-window capacity for 32 rows (mean 512, sd ~23)

typedef float f32x4 __attribute__((ext_vector_type(4)));
typedef short s16x8 __attribute__((ext_vector_type(8)));

__device__ __forceinline__ unsigned short f2bf(float f) {
  unsigned u = __builtin_bit_cast(unsigned, f);
  unsigned r = u + 0x7FFFu + ((u >> 16) & 1u);
  return (unsigned short)(r >> 16);
}
__device__ __forceinline__ float bf2f(unsigned short u) {
  return __builtin_bit_cast(float, (unsigned)u << 16);
}
__device__ __forceinline__ void gload_lds16(const void* g, void* l) {
  __builtin_amdgcn_global_load_lds(
      (const __attribute__((address_space(1))) unsigned*)g,
      (__attribute__((address_space(3))) unsigned*)l, 16, 0, 0);
}

// ---- per-(graph,dst,relation) segment count, both graphs ----
__global__ void k_count(const int* __restrict__ ei, const int* __restrict__ et,
                        int* __restrict__ cnt) {
  int e = blockIdx.x * blockDim.x + threadIdx.x;  // 0..2*EE
  int g = e >= EE;
  int el = e - g * EE;
  int d = ei[(size_t)g * 2 * EE + EE + el];
  int t = et[(size_t)g * EE + el];
  atomicAdd(&cnt[(size_t)g * NR + d * RR + t], 1);
}

// ---- hierarchical exclusive scan ----
__global__ __launch_bounds__(1024) void k_scan1(const int* __restrict__ cnt,
                                                int* __restrict__ off,
                                                int* __restrict__ btot) {
  int g = blockIdx.y, b = blockIdx.x;
  const int* c = cnt + (size_t)g * NR;
  int* o = off + (size_t)g * NR;
  __shared__ int wsum[16];
  int lane = threadIdx.x & 63, w = threadIdx.x >> 6;
  int i = b * 4096 + (int)threadIdx.x * 4;
  int4 v = {0, 0, 0, 0};
  if (i + 3 < NR) v = *(const int4*)&c[i];
  else {
    if (i < NR) v.x = c[i];
    if (i + 1 < NR) v.y = c[i + 1];
    if (i + 2 < NR) v.z = c[i + 2];
  }
  int s0 = v.x, s1 = s0 + v.y, s2 = s1 + v.z, s3 = s2 + v.w;
  int s = s3;
  for (int d = 1; d < 64; d <<= 1) {
    int t = __shfl_up(s, d);
    if (lane >= d) s += t;
  }
  if (lane == 63) wsum[w] = s;
  __syncthreads();
  if (threadIdx.x < 16) {
    int ws = wsum[threadIdx.x];
    for (int d = 1; d < 16; d <<= 1) {
      int t = __shfl_up(ws, d);
      if ((int)threadIdx.x >= d) ws += t;
    }
    wsum[threadIdx.x] = ws;
  }
  __syncthreads();
  int excl = (w > 0 ? wsum[w - 1] : 0) + (s - s3);
  if (i < NR) o[i] = excl;
  if (i + 1 < NR) o[i + 1] = excl + s0;
  if (i + 2 < NR) o[i + 2] = excl + s1;
  if (i + 3 < NR) o[i + 3] = excl + s2;
  if (threadIdx.x == 0) btot[g * NB + b] = wsum[15];
}

__global__ void k_scan2(const int* __restrict__ btot, int* __restrict__ bof) {
  int g = threadIdx.x >> 6, lane = threadIdx.x & 63;
  int v = (lane < NB) ? btot[g * NB + lane] : 0;
  int s = v;
  for (int d = 1; d < 64; d <<= 1) {
    int t = __shfl_up(s, d);
    if (lane >= d) s += t;
  }
  if (lane < NB) bof[g * NB + lane] = s - v;
}

__global__ __launch_bounds__(1024) void k_scan3(int* __restrict__ off,
                                                const int* __restrict__ bof) {
  int g = blockIdx.y;
  int add = bof[g * NB + blockIdx.x];
  int i = blockIdx.x * 4096 + (int)threadIdx.x * 4;
  int* o = off + (size_t)g * NR;
  if (i + 3 < NR) {
    int4 v = *(const int4*)&o[i];
    v.x += add; v.y += add; v.z += add; v.w += add;
    *(int4*)&o[i] = v;
  } else {
    for (int j = i; j < NR; ++j) o[j] += add;
  }
}

// ---- scatter src ids; DESTROYS off: post-scatter off[s] = end of segment s ----
__global__ void k_scatter(const int* __restrict__ ei, const int* __restrict__ et,
                          int* __restrict__ off, int* __restrict__ ssrc) {
  int e = blockIdx.x * blockDim.x + threadIdx.x;
  int g = e >= EE;
  int el = e - g * EE;
  int s = ei[(size_t)g * 2 * EE + el];
  int d = ei[(size_t)g * 2 * EE + EE + el];
  int t = et[(size_t)g * EE + el];
  int pos = atomicAdd(&off[(size_t)g * NR + d * RR + t], 1);
  ssrc[(size_t)g * EE + pos] = s;
}

// ---- fp32 x -> bf16, both graphs, into per-graph NN*256-strided slots ----
__global__ void k_cvt(const float* __restrict__ x, unsigned short* __restrict__ hX) {
  int i = (blockIdx.x * blockDim.x + threadIdx.x) * 4;
  if (i >= 2 * NN * 128) return;
  int g = i >= NN * 128;
  int il = i - g * NN * 128;
  float4 v = *(const float4*)&x[i];
  ushort4 o;
  o.x = f2bf(v.x); o.y = f2bf(v.y); o.z = f2bf(v.z); o.w = f2bf(v.w);
  *(ushort4*)&hX[(size_t)g * NN * 256 + il] = o;
}

// ---- bf16 transposed weight panel BT[co][k], k = r*Cin+ci (r=8 -> root) ----
__global__ void k_bt(const float* __restrict__ W, const float* __restrict__ root,
                     unsigned short* __restrict__ bt, int Cin, int Cout, int Ktot) {
  int idx = blockIdx.x * blockDim.x + threadIdx.x;
  if (idx >= Cout * Ktot) return;
  int co = idx / Ktot, k = idx - co * Ktot;
  int r = k / Cin, ci = k - r * Cin;
  float v = (r < RR) ? W[((size_t)r * Cin + ci) * Cout + co]
                     : root[(size_t)ci * Cout + co];
  bt[idx] = f2bf(v);
}

// MFMA on the current 32-row x COUT x 64-K tile in LDS
#define MFMA_STEP()                                                            \
  do {                                                                         \
    _Pragma("unroll") for (int kk = 0; kk < 2; ++kk) {                         \
      s16x8 a[MF], b[4];                                                       \
      _Pragma("unroll") for (int f = 0; f < MF; ++f) {                         \
        int row = wm + f * 16 + (lane & 15);                                   \
        int colb = kk * 64 + (lane >> 4) * 16;                                 \
        a[f] = *(const s16x8*)((const char*)As + row * 128 +                   \
                               (colb ^ ((row & 7) << 4)));                     \
      }                                                                        \
      _Pragma("unroll") for (int f = 0; f < 4; ++f) {                          \
        int row = wn + f * 16 + (lane & 15);                                   \
        int colb = kk * 64 + (lane >> 4) * 16;                                 \
        b[f] = *(const s16x8*)((const char*)Bs + row * 128 +                   \
                               (colb ^ ((row & 7) << 4)));                     \
      }                                                                        \
      _Pragma("unroll") for (int fm = 0; fm < MF; ++fm)                        \
          _Pragma("unroll") for (int fn = 0; fn < 4; ++fn)                     \
              acc[fm][fn] = __builtin_amdgcn_mfma_f32_16x16x32_bf16(           \
                  a[fm], b[fn], acc[fm][fn], 0, 0, 0);                         \
    }                                                                          \
  } while (0)

// ---- fused gather+GEMM, 32-row x COUT tile, 8 threads/row, walk-once ----
template <int CIN, int COUT, bool OUTF32>
__global__ __launch_bounds__(256, 2) void k_fused(
    const int* __restrict__ ssrc, const int* __restrict__ off,
    const unsigned short* __restrict__ h, const unsigned short* __restrict__ bt,
    const float* __restrict__ bias, void* __restrict__ outp) {
  constexpr int KTOT = (RR + 1) * CIN;
  constexpr int CH = CIN / 64;     // K-steps per relation (2 or 4)
  constexpr int CPT = CIN / 8;     // cols per thread (16 or 32)
  constexpr int NCH = CPT / 8;     // 16B chunks per thread (2 or 4)
  constexpr int NWN = COUT / 64;   // n-waves (4 or 2)
  constexpr int MW = 4 / NWN;      // m-waves (1 or 2)
  constexpr int WR = 32 / MW;      // rows per wave (32 or 16)
  constexpr int MF = WR / 16;      // m-frags per wave (2 or 1)
  constexpr int BCH = COUT / 32;   // B 16B-chunks per thread (8 or 4)
  __shared__ unsigned short As[32 * 64];
  __shared__ unsigned short Bs[COUT * 64];
  __shared__ int offs[32][9];      // per-row segment boundaries (start + 8 ends)
  __shared__ int sseg[SCAP];       // this block's sorted-edge window
  const int tid = threadIdx.x, lane = tid & 63, wave = tid >> 6;
  const int wn = (wave % NWN) * 64;
  const int wm = (wave / NWN) * WR;
  const int m0 = blockIdx.x * 32;  // NN == 625*32, no clamps needed
  const int g = blockIdx.z;
  ssrc += (size_t)g * EE;
  off += (size_t)g * NR;
  h += (size_t)g * NN * 256;

  for (int idx = tid; idx < 32 * 9; idx += 256) {
    int row = idx / 9, j = idx - row * 9;
    int seg0 = (m0 + row) * RR;
    offs[row][j] = (j == 0) ? (seg0 == 0 ? 0 : off[seg0 - 1]) : off[seg0 + j - 1];
  }
  // block edge window [ebase, eend): rows' segments are contiguous in ssrc
  const int segA = m0 * RR;
  const int ebase = (segA == 0) ? 0 : off[segA - 1];
  const int eend = off[(m0 + 32) * RR - 1];
  const int cntE = eend - ebase;
  const bool inl = cntE <= SCAP;
  if (inl)
    for (int i = tid; i < cntE; i += 256) sseg[i] = ssrc[ebase + i];
  __syncthreads();

  f32x4 acc[MF][4] = {};
  const int arow = tid >> 3;              // this thread's A row (0..31)
  const int q = tid & 7;                  // 8 threads/row, CPT cols each
  const int myc = (q * CPT) >> 6;         // the K-step this thread's cols fall in
  const int mycolb = ((q * CPT) & 63) * 2;  // byte col within that 64-col window
  const int swzA = (arow & 7) << 4;
  const unsigned short* hq = h + q * CPT;

  for (int r = 0; r < RR; ++r) {
    // ---- walk this relation's segment ONCE, CPT-col fp32 accumulation ----
    float fa[NCH][8];
#pragma unroll
    for (int c = 0; c < NCH; ++c)
#pragma unroll
      for (int j = 0; j < 8; ++j) fa[c][j] = 0.f;
    int o0 = offs[arow][r], o1 = offs[arow][r + 1];
    int e = o0;
    for (; e + 1 < o1; e += 2) {
      int sa = inl ? sseg[e - ebase] : ssrc[e];
      int sb = inl ? sseg[e + 1 - ebase] : ssrc[e + 1];
      const unsigned short* pa = hq + (size_t)sa * CIN;
      const unsigned short* pb = hq + (size_t)sb * CIN;
#pragma unroll
      for (int c = 0; c < NCH; ++c) {
        s16x8 va = *(const s16x8*)(pa + c * 8);
        s16x8 vb = *(const s16x8*)(pb + c * 8);
#pragma unroll
        for (int j = 0; j < 8; ++j)
          fa[c][j] += bf2f((unsigned short)va[j]) + bf2f((unsigned short)vb[j]);
      }
    }
    if (e < o1) {
      int sa = inl ? sseg[e - ebase] : ssrc[e];
      const unsigned short* pa = hq + (size_t)sa * CIN;
#pragma unroll
      for (int c = 0; c < NCH; ++c) {
        s16x8 va = *(const s16x8*)(pa + c * 8);
#pragma unroll
        for (int j = 0; j < 8; ++j) fa[c][j] += bf2f((unsigned short)va[j]);
      }
    }
    float inv = 1.0f / fmaxf((float)(o1 - o0), 1.0f);
    s16x8 mb[NCH];
#pragma unroll
    for (int c = 0; c < NCH; ++c)
#pragma unroll
      for (int j = 0; j < 8; ++j) mb[c][j] = (short)f2bf(fa[c][j] * inv);
    // ---- drain: CH K-steps of 64 cols each ----
#pragma unroll
    for (int c = 0; c < CH; ++c) {
      const int k0 = r * CIN + c * 64;
#pragma unroll
      for (int i = 0; i < BCH; ++i) {
        int ldsb = (wave * BCH + i) * 1024;
        int Wb = ldsb + lane * 16;
        int brow = Wb >> 7;
        int colb = (Wb & 127) ^ ((brow & 7) << 4);
        gload_lds16((const char*)bt + ((size_t)brow * KTOT + k0) * 2 + colb,
                    (char*)Bs + ldsb);
      }
      if (c == myc) {
        char* Ab = (char*)As + arow * 128;
#pragma unroll
        for (int ch = 0; ch < NCH; ++ch)
          *(s16x8*)(Ab + ((mycolb + ch * 16) ^ swzA)) = mb[ch];
      }
      __syncthreads();
      MFMA_STEP();
      __syncthreads();
    }
  }
  // ---- root term: stage A directly from h ----
#pragma unroll
  for (int c = 0; c < CH; ++c) {
    const int k0 = RR * CIN + c * 64;
#pragma unroll
    for (int i = 0; i < BCH; ++i) {
      int ldsb = (wave * BCH + i) * 1024;
      int Wb = ldsb + lane * 16;
      int brow = Wb >> 7;
      int colb = (Wb & 127) ^ ((brow & 7) << 4);
      gload_lds16((const char*)bt + ((size_t)brow * KTOT + k0) * 2 + colb,
                  (char*)Bs + ldsb);
    }
    {
      int ldsb = wave * 1024;  // 4 KB A tile, 1 KB per wave
      int Wb = ldsb + lane * 16;
      int row = Wb >> 7;
      int colb = (Wb & 127) ^ ((row & 7) << 4);
      gload_lds16((const char*)h + ((size_t)(m0 + row) * CIN + c * 64) * 2 + colb,
                  (char*)As + ldsb);
    }
    __syncthreads();
    MFMA_STEP();
    __syncthreads();
  }
  // ---- epilogue: bias + LeakyReLU ----
#pragma unroll
  for (int fm = 0; fm < MF; ++fm) {
    int rbase = m0 + wm + fm * 16 + (lane >> 4) * 4;
#pragma unroll
    for (int fn = 0; fn < 4; ++fn) {
      int col = wn + fn * 16 + (lane & 15);
      float bv = bias[col];
#pragma unroll
      for (int v = 0; v < 4; ++v) {
        int row = rbase + v;
        float xv = acc[fm][fn][v] + bv;
        xv = xv > 0.f ? xv : 0.2f * xv;
        if constexpr (OUTF32)
          ((float*)outp)[(size_t)g * NN * COUT + (size_t)row * COUT + col] = xv;
        else
          ((unsigned short*)outp)[(size_t)g * NN * 256 + (size_t)row * COUT +
                                  col] = f2bf(xv);
      }
    }
  }
}

extern "C" void kernel_launch(void* const* d_in, const int* in_sizes, int n_in,
                              void* d_out, int out_size, void* d_ws, size_t ws_size,
                              hipStream_t stream) {
  const float* x  = (const float*)d_in[0];
  const int* ei   = (const int*)d_in[1];
  const int* etp  = (const int*)d_in[2];
  const float* W0 = (const float*)d_in[3];
  const float* r0 = (const float*)d_in[4];
  const float* b0 = (const float*)d_in[5];
  const float* W1 = (const float*)d_in[6];
  const float* r1 = (const float*)d_in[7];
  const float* b1 = (const float*)d_in[8];
  const float* W2 = (const float*)d_in[9];
  const float* r2 = (const float*)d_in[10];
  const float* b2 = (const float*)d_in[11];

  char* p = (char*)d_ws;
  unsigned short* hX  = (unsigned short*)p; p += (size_t)2 * NN * 256 * 2;
  unsigned short* h_a = (unsigned short*)p; p += (size_t)2 * NN * 256 * 2;
  int* cnt  = (int*)p; p += (size_t)2 * NR * 4;
  int* off  = (int*)p; p += (size_t)2 * NR * 4;
  int* btot = (int*)p; p += (size_t)2 * NB * 4;
  int* bof  = (int*)p; p += (size_t)2 * NB * 4;
  int* ssrc = (int*)p; p += (size_t)2 * EE * 4;
  unsigned short* bt0 = (unsigned short*)p; p += (size_t)256 * 1152 * 2;
  unsigned short* bt1 = (unsigned short*)p; p += (size_t)256 * 2304 * 2;
  unsigned short* bt2 = (unsigned short*)p; p += (size_t)128 * 2304 * 2;

  // weight panels (graph-independent)
  k_bt<<<(256 * 1152 + 255) / 256, 256, 0, stream>>>(W0, r0, bt0, 128, 256, 1152);
  k_bt<<<(256 * 2304 + 255) / 256, 256, 0, stream>>>(W1, r1, bt1, 256, 256, 2304);
  k_bt<<<(128 * 2304 + 255) / 256, 256, 0, stream>>>(W2, r2, bt2, 256, 128, 2304);

  // edge sort (both graphs batched)
  (void)hipMemsetAsync(cnt, 0, (size_t)2 * NR * 4, stream);
  k_count<<<2 * EE / 256, 256, 0, stream>>>(ei, etp, cnt);
  k_scan1<<<dim3(NB, 2), 1024, 0, stream>>>(cnt, off, btot);
  k_scan2<<<1, 128, 0, stream>>>(btot, bof);
  k_scan3<<<dim3(NB, 2), 1024, 0, stream>>>(off, bof);
  k_cvt<<<2 * NN * 128 / 4 / 256, 256, 0, stream>>>(x, hX);
  k_scatter<<<2 * EE / 256, 256, 0, stream>>>(ei, etp, off, ssrc);

  // layer 0: 128 -> 256 (fused gather+GEMM)
  k_fused<128, 256, false><<<dim3(625, 1, 2), 256, 0, stream>>>(
      ssrc, off, hX, bt0, b0, h_a);
  // layer 1: 256 -> 256
  k_fused<256, 256, false><<<dim3(625, 1, 2), 256, 0, stream>>>(
      ssrc, off, h_a, bt1, b1, hX);
  // layer 2: 256 -> 128
  k_fused<256, 128, true><<<dim3(625, 1, 2), 256, 0, stream>>>(
      ssrc, off, hX, bt2, b2, d_out);
}